// Round 13
// baseline (41.628 us; speedup 1.0000x reference)
//
#include <hip/hip_runtime.h>

// DifferentiableCIndexLoss:
//   mask[i,j] = (t[i] < t[j]) && (e[i]==1)
//   loss = sum sigmoid((r[j]-r[i])/SIGMA) * mask ;  count = sum mask
//   out  = loss / (count + 1e-6)
//
// R13 = R12 (best, 40.9us) with the LDS j-tile REMOVED: the j values are
// block-uniform, so k_main reads them directly from global with uniform
// indices -- LLVM uniformity analysis should emit s_load_dwordx2 (scalar
// pipe, SGPR broadcast, prefetched by unroll), freeing the VALU/LDS path
// entirely and deleting both per-tile barriers + all ds_reads.
// Rationale: R11 (paired-rcp) and R12 (half the blocks) were ~neutral =>
// main's ~2x gap over its ~14us VALU floor is the staging path (ds_read
// pipe occupancy ~= VALU time at 16 waves/CU + lgkmcnt/barrier waits).
// sJ re-read traffic = nrc*B*8B ~= 1 MB, L2-resident.
// Kept: pre-transformed sI=(2^s,t)/sJ=(2^-s,t), paired-rcp, finite pads,
// plain partial stores + double finalize, no device-scope fences/spins.
//   s = r*log2e/sigma clamped to +-60: 2^{si-sj} in [2^-120,2^120].

#define BLOCK 256
#define RPT 4                        // rows per thread
#define ROWS_PER_TILE (BLOCK * RPT)  // 1024
#define JTILE 128                    // cols per tile
#define NCOLGRP 128                  // 16384/128
#define GRID_MAIN 1024

__device__ __forceinline__ float fast_exp2(float x) { return __builtin_amdgcn_exp2f(x); }
__device__ __forceinline__ float fast_rcp(float x)  { return __builtin_amdgcn_rcpf(x); }
__device__ __forceinline__ float clamp60(float x)   { return fminf(fmaxf(x, -60.0f), 60.0f); }

// ---- 1) transform cols + compact active rows (block-aggregated cursor) ------
__global__ __launch_bounds__(BLOCK) void k_compact(
    const float* __restrict__ r, const float* __restrict__ t,
    const int* __restrict__ ev, int B, float kscale,
    int* __restrict__ cursor,          // zeroed by memset; final value = nactive
    float2* __restrict__ sI, float2* __restrict__ sJ) {
    const int tid = threadIdx.x;
    int g = blockIdx.x * BLOCK + tid;
    if (g >= B) return;
    float tv = t[g];
    float s  = clamp60(r[g] * kscale);
    sJ[g] = make_float2(fast_exp2(-s), tv);        // F_j = 2^{-s_j}
    bool pred = (ev[g] == 1);
    unsigned long long bal = __ballot(pred);
    int lane = tid & 63, wid = tid >> 6;
    int before = __popcll(bal & ((1ull << lane) - 1ull));
    int wcnt = __popcll(bal);
    __shared__ int wbase[BLOCK / 64];
    if (lane == 0) wbase[wid] = wcnt;
    __syncthreads();
    if (tid == 0) {
        int c0 = wbase[0], c1 = wbase[1], c2 = wbase[2], c3 = wbase[3];
        int b0 = atomicAdd(cursor, (c0 + c1) + (c2 + c3));  // ONE atomic/block
        wbase[0] = b0; wbase[1] = b0 + c0; wbase[2] = b0 + c0 + c1;
        wbase[3] = b0 + c0 + c1 + c2;
    }
    __syncthreads();
    if (pred) sI[wbase[wid] + before] = make_float2(fast_exp2(s), tv);
}

// ---- 2) main: all-pairs, j-values via UNIFORM (scalar-pipe) global reads ----
__global__ __launch_bounds__(BLOCK) void k_main(
    const float2* __restrict__ sI, const float2* __restrict__ sJ,
    const int* __restrict__ nactive_g,
    float* __restrict__ pL, unsigned int* __restrict__ pC) {

    const int tid = threadIdx.x;
    const int nactive = *nactive_g;
    const int nrc = (nactive + ROWS_PER_TILE - 1) / ROWS_PER_TILE;  // ~8
    const int ntiles = nrc * NCOLGRP;                                // ~1024

    float lsum = 0.0f;
    int   csum = 0;

    for (int tix = blockIdx.x; tix < ntiles; tix += gridDim.x) {
        int rc = tix >> 7;            // row chunk (ntiles = nrc*128)
        int cg = tix & (NCOLGRP - 1); // col group

        // 4 rows/thread, coalesced float2 loads, once per tile (128 cols reuse)
        float E[RPT], T[RPT];
        int rbase = rc * ROWS_PER_TILE;
#pragma unroll
        for (int k = 0; k < RPT; ++k) {
            int rr = rbase + tid + (k << 8);
            if (rr < nactive) { float2 f = sI[rr]; E[k] = f.x; T[k] = f.y; }
            else              { E[k] = 1.0f; T[k] = 3.0f; }
            // pad: FINITE E (mask kills num & count); NOT inf (shared product!)
        }

        // j values: block-uniform address -> scalar loads, no LDS, no barriers
        const float2* __restrict__ col = sJ + (cg << 7);

        float l0 = 0.f, l1 = 0.f;
        int c = 0;
#pragma unroll 8
        for (int jj = 0; jj < JTILE; ++jj) {
            float2 q = col[jj];       // uniform: s_load_dwordx2 expected
            float F = q.x, tj = q.y;
            // pairs (0,1): one rcp for two sigmoids
            float u0 = __builtin_fmaf(E[0], F, 1.0f);
            float v0 = __builtin_fmaf(E[1], F, 1.0f);
            float p0 = fminf(u0 * v0, 3.0e38f);
            float rp0 = fast_rcp(p0);
            bool m0 = T[0] < tj, m1 = T[1] < tj;
            float num0 = (m0 ? v0 : 0.0f) + (m1 ? u0 : 0.0f);
            l0 = __builtin_fmaf(num0, rp0, l0);
            c += m0; c += m1;
            // pairs (2,3)
            float u1 = __builtin_fmaf(E[2], F, 1.0f);
            float v1 = __builtin_fmaf(E[3], F, 1.0f);
            float p1 = fminf(u1 * v1, 3.0e38f);
            float rp1 = fast_rcp(p1);
            bool m2 = T[2] < tj, m3 = T[3] < tj;
            float num1 = (m2 ? v1 : 0.0f) + (m3 ? u1 : 0.0f);
            l1 = __builtin_fmaf(num1, rp1, l1);
            c += m2; c += m3;
        }
        lsum += l0 + l1;
        csum += c;
    }

    // block reduce + plain partial stores
#pragma unroll
    for (int off = 32; off > 0; off >>= 1) {
        lsum += __shfl_down(lsum, off);
        csum += __shfl_down(csum, off);
    }
    __shared__ float lw[BLOCK / 64];
    __shared__ int   cw[BLOCK / 64];
    int wid = tid >> 6;
    if ((tid & 63) == 0) { lw[wid] = lsum; cw[wid] = csum; }
    __syncthreads();
    if (tid == 0) {
        pL[blockIdx.x] = (lw[0] + lw[1]) + (lw[2] + lw[3]);
        pC[blockIdx.x] = (unsigned)((cw[0] + cw[1]) + (cw[2] + cw[3]));
    }
}

// ---- 3) finalize -------------------------------------------------------------
__global__ __launch_bounds__(BLOCK) void k_finalize(
    const float* __restrict__ pL, const unsigned int* __restrict__ pC,
    int n, float* __restrict__ out) {
    double l = 0.0, c = 0.0;
    for (int i = threadIdx.x; i < n; i += BLOCK) {
        l += (double)pL[i];
        c += (double)pC[i];
    }
#pragma unroll
    for (int off = 32; off > 0; off >>= 1) {
        l += __shfl_down(l, off);
        c += __shfl_down(c, off);
    }
    __shared__ double lw[BLOCK / 64], cw[BLOCK / 64];
    int wid = threadIdx.x >> 6;
    if ((threadIdx.x & 63) == 0) { lw[wid] = l; cw[wid] = c; }
    __syncthreads();
    if (threadIdx.x == 0) {
        double L = (lw[0] + lw[1]) + (lw[2] + lw[3]);
        double C = (cw[0] + cw[1]) + (cw[2] + cw[3]);
        out[0] = (float)(L / (C + 1e-6));
    }
}

extern "C" void kernel_launch(void* const* d_in, const int* in_sizes, int n_in,
                              void* d_out, int out_size, void* d_ws, size_t ws_size,
                              hipStream_t stream) {
    const float* r  = (const float*)d_in[0];
    const float* t  = (const float*)d_in[1];
    const int*   ev = (const int*)d_in[2];
    float* out = (float*)d_out;
    const int B = in_sizes[0];   // 16384

    const float SIGMA = 0.1f;
    const float LOG2E = 1.4426950408889634f;
    const float kscale = LOG2E / SIGMA;

    char* ws = (char*)d_ws;
    int* cursor = (int*)ws;                        // [0,64): atomic cursor = nactive
    float2* sI  = (float2*)(ws + 4096);            // 128 KB (compacted rows: E, t)
    float2* sJ  = sI + B;                          // 128 KB (all cols: F, t)
    float*  pL  = (float*)(sJ + B);
    unsigned int* pC = (unsigned int*)(pL + GRID_MAIN);

    const int nblk = (B + BLOCK - 1) / BLOCK;      // 64

    hipMemsetAsync(ws, 0, 64, stream);
    k_compact<<<nblk, BLOCK, 0, stream>>>(r, t, ev, B, kscale, cursor, sI, sJ);
    k_main<<<GRID_MAIN, BLOCK, 0, stream>>>(sI, sJ, cursor, pL, pC);
    k_finalize<<<1, BLOCK, 0, stream>>>(pL, pC, GRID_MAIN, out);
}

// Round 14
// 40.622 us; speedup vs baseline: 1.0247x; 1.0247x over previous
//
#include <hip/hip_runtime.h>

// DifferentiableCIndexLoss:
//   mask[i,j] = (t[i] < t[j]) && (e[i]==1)
//   loss = sum sigmoid((r[j]-r[i])/SIGMA) * mask ;  count = sum mask
//   out  = loss / (count + 1e-6)
//
// R14 = R12 (best, 40.9us) with ILP restored. Evidence: occupancy pins at
// ~48% (16 waves/CU) at ANY grid size, so latency hiding must come from
// per-wave ILP; R2 (RPT=8, separate loss+cnt chains) measured 72% VALUBusy,
// R10-13 (RPT=4, merged cnt chain since R11) ~50%. Change the DEPENDENCY
// STRUCTURE only, instruction count ~unchanged (discriminates latency vs
// issue): RPT=8 rows/thread; 4 paired-rcp groups each with OWN l and OWN c
// accumulator => 8 independent fp chains + 4 independent int chains.
// Kept: pre-transformed sI=(2^s,t)/sJ=(2^-s,t), LDS j-tile (R12>R13 uniform),
// JTILE=64, grid 1024 (ntiles=4*256=1024), plain partial stores + double
// finalize, no device-scope fences/atomics/spins in hot path.
//   s = r*log2e/sigma clamped to +-60: 2^{si-sj} in [2^-120,2^120].

#define BLOCK 256
#define RPT 8                        // rows per thread
#define ROWS_PER_TILE (BLOCK * RPT)  // 2048
#define JTILE 64                     // cols per tile
#define NCOLGRP 256                  // 16384/64
#define GRID_MAIN 1024               // = nrc(4) * 256

__device__ __forceinline__ float fast_exp2(float x) { return __builtin_amdgcn_exp2f(x); }
__device__ __forceinline__ float fast_rcp(float x)  { return __builtin_amdgcn_rcpf(x); }
__device__ __forceinline__ float clamp60(float x)   { return fminf(fmaxf(x, -60.0f), 60.0f); }

// ---- 1) transform cols + compact active rows (block-aggregated cursor) ------
__global__ __launch_bounds__(BLOCK) void k_compact(
    const float* __restrict__ r, const float* __restrict__ t,
    const int* __restrict__ ev, int B, float kscale,
    int* __restrict__ cursor,          // zeroed by memset; final value = nactive
    float2* __restrict__ sI, float2* __restrict__ sJ) {
    const int tid = threadIdx.x;
    int g = blockIdx.x * BLOCK + tid;
    if (g >= B) return;
    float tv = t[g];
    float s  = clamp60(r[g] * kscale);
    sJ[g] = make_float2(fast_exp2(-s), tv);        // F_j = 2^{-s_j}
    bool pred = (ev[g] == 1);
    unsigned long long bal = __ballot(pred);
    int lane = tid & 63, wid = tid >> 6;
    int before = __popcll(bal & ((1ull << lane) - 1ull));
    int wcnt = __popcll(bal);
    __shared__ int wbase[BLOCK / 64];
    if (lane == 0) wbase[wid] = wcnt;
    __syncthreads();
    if (tid == 0) {
        int c0 = wbase[0], c1 = wbase[1], c2 = wbase[2], c3 = wbase[3];
        int b0 = atomicAdd(cursor, (c0 + c1) + (c2 + c3));  // ONE atomic/block
        wbase[0] = b0; wbase[1] = b0 + c0; wbase[2] = b0 + c0 + c1;
        wbase[3] = b0 + c0 + c1 + c2;
    }
    __syncthreads();
    if (pred) sI[wbase[wid] + before] = make_float2(fast_exp2(s), tv);
}

// ---- 2) main: all-pairs, RPT=8, independent accumulator chains --------------
__global__ __launch_bounds__(BLOCK) void k_main(
    const float2* __restrict__ sI, const float2* __restrict__ sJ,
    const int* __restrict__ nactive_g,
    float* __restrict__ pL, unsigned int* __restrict__ pC) {

    const int tid = threadIdx.x;
    const int nactive = *nactive_g;
    const int nrc = (nactive + ROWS_PER_TILE - 1) / ROWS_PER_TILE;  // ~4
    const int ntiles = nrc * NCOLGRP;                                // ~1024

    __shared__ float2 tile[JTILE];

    float lsum = 0.0f;
    int   csum = 0;

    for (int tix = blockIdx.x; tix < ntiles; tix += gridDim.x) {
        int rc = tix >> 8;            // row chunk (ntiles = nrc*256)
        int cg = tix & (NCOLGRP - 1); // col group

        // 8 rows/thread, coalesced float2 loads, once per tile
        float E[RPT], T[RPT];
        int rbase = rc * ROWS_PER_TILE;
#pragma unroll
        for (int k = 0; k < RPT; ++k) {
            int rr = rbase + tid + (k << 8);
            if (rr < nactive) { float2 f = sI[rr]; E[k] = f.x; T[k] = f.y; }
            else              { E[k] = 1.0f; T[k] = 3.0f; }
            // pad: FINITE E (mask kills num & count); NOT inf (shared product!)
        }

        __syncthreads();              // protect tile[] from previous iteration
        if (tid < JTILE) tile[tid] = sJ[(cg << 6) + tid];
        __syncthreads();

        float l[4] = {0.f, 0.f, 0.f, 0.f};
        int   c[4] = {0, 0, 0, 0};
#pragma unroll 4
        for (int jj = 0; jj < JTILE; ++jj) {
            float2 q = tile[jj];      // wave-uniform LDS broadcast
            float F = q.x, tj = q.y;
#pragma unroll
            for (int g2 = 0; g2 < 4; ++g2) {      // 4 independent pair-groups
                float u = __builtin_fmaf(E[2*g2],   F, 1.0f);
                float v = __builtin_fmaf(E[2*g2+1], F, 1.0f);
                float p = fminf(u * v, 3.0e38f);
                float rp = fast_rcp(p);
                bool m0 = T[2*g2]   < tj;
                bool m1 = T[2*g2+1] < tj;
                float num = (m0 ? v : 0.0f) + (m1 ? u : 0.0f);
                l[g2] = __builtin_fmaf(num, rp, l[g2]);   // own fp chain
                c[g2] += m0 + m1;                          // own int chain
            }
        }
        lsum += (l[0] + l[1]) + (l[2] + l[3]);
        csum += (c[0] + c[1]) + (c[2] + c[3]);
    }

    // block reduce + plain partial stores
#pragma unroll
    for (int off = 32; off > 0; off >>= 1) {
        lsum += __shfl_down(lsum, off);
        csum += __shfl_down(csum, off);
    }
    __shared__ float lw[BLOCK / 64];
    __shared__ int   cw[BLOCK / 64];
    int wid = tid >> 6;
    if ((tid & 63) == 0) { lw[wid] = lsum; cw[wid] = csum; }
    __syncthreads();
    if (tid == 0) {
        pL[blockIdx.x] = (lw[0] + lw[1]) + (lw[2] + lw[3]);
        pC[blockIdx.x] = (unsigned)((cw[0] + cw[1]) + (cw[2] + cw[3]));
    }
}

// ---- 3) finalize -------------------------------------------------------------
__global__ __launch_bounds__(BLOCK) void k_finalize(
    const float* __restrict__ pL, const unsigned int* __restrict__ pC,
    int n, float* __restrict__ out) {
    double l = 0.0, c = 0.0;
    for (int i = threadIdx.x; i < n; i += BLOCK) {
        l += (double)pL[i];
        c += (double)pC[i];
    }
#pragma unroll
    for (int off = 32; off > 0; off >>= 1) {
        l += __shfl_down(l, off);
        c += __shfl_down(c, off);
    }
    __shared__ double lw[BLOCK / 64], cw[BLOCK / 64];
    int wid = threadIdx.x >> 6;
    if ((threadIdx.x & 63) == 0) { lw[wid] = l; cw[wid] = c; }
    __syncthreads();
    if (threadIdx.x == 0) {
        double L = (lw[0] + lw[1]) + (lw[2] + lw[3]);
        double C = (cw[0] + cw[1]) + (cw[2] + cw[3]);
        out[0] = (float)(L / (C + 1e-6));
    }
}

extern "C" void kernel_launch(void* const* d_in, const int* in_sizes, int n_in,
                              void* d_out, int out_size, void* d_ws, size_t ws_size,
                              hipStream_t stream) {
    const float* r  = (const float*)d_in[0];
    const float* t  = (const float*)d_in[1];
    const int*   ev = (const int*)d_in[2];
    float* out = (float*)d_out;
    const int B = in_sizes[0];   // 16384

    const float SIGMA = 0.1f;
    const float LOG2E = 1.4426950408889634f;
    const float kscale = LOG2E / SIGMA;

    char* ws = (char*)d_ws;
    int* cursor = (int*)ws;                        // [0,64): atomic cursor = nactive
    float2* sI  = (float2*)(ws + 4096);            // 128 KB (compacted rows: E, t)
    float2* sJ  = sI + B;                          // 128 KB (all cols: F, t)
    float*  pL  = (float*)(sJ + B);
    unsigned int* pC = (unsigned int*)(pL + GRID_MAIN);

    const int nblk = (B + BLOCK - 1) / BLOCK;      // 64

    hipMemsetAsync(ws, 0, 64, stream);
    k_compact<<<nblk, BLOCK, 0, stream>>>(r, t, ev, B, kscale, cursor, sI, sJ);
    k_main<<<GRID_MAIN, BLOCK, 0, stream>>>(sI, sJ, cursor, pL, pC);
    k_finalize<<<1, BLOCK, 0, stream>>>(pL, pC, GRID_MAIN, out);
}